// Round 12
// baseline (234.594 us; speedup 1.0000x reference)
//
#include <hip/hip_runtime.h>
#include <stdint.h>

#define B_DIM 8192
#define K_DIM 2048
#define N_DIM 2048
#define NSEG 4
#define NT (K_DIM / 64)   // 32 K-tiles of BK=64

typedef int v4i __attribute__((ext_vector_type(4)));

typedef const __attribute__((address_space(1))) void* gas_ptr;
typedef __attribute__((address_space(3))) void* lds_ptr;

// ---- fused: x row quantize (per-row int8) + gates = sigmoid(x@Wg^T+bg) ----
__global__ __launch_bounds__(256)
void xquant_gates_kernel(const float* __restrict__ x, const float* __restrict__ Wg,
                         const float* __restrict__ bg, signed char* __restrict__ xq,
                         float* __restrict__ sx, float* __restrict__ gates) {
  const int b = blockIdx.x;
  const int tid = threadIdx.x;
  const size_t base = (size_t)b * K_DIM + tid * 8;
  const float4 v0 = *(const float4*)(x + base);
  const float4 v1 = *(const float4*)(x + base + 4);

  float a[4];
#pragma unroll
  for (int s = 0; s < 4; ++s) {
    const float4 w0 = *(const float4*)(Wg + (size_t)s * K_DIM + tid * 8);
    const float4 w1 = *(const float4*)(Wg + (size_t)s * K_DIM + tid * 8 + 4);
    a[s] = v0.x * w0.x + v0.y * w0.y + v0.z * w0.z + v0.w * w0.w
         + v1.x * w1.x + v1.y * w1.y + v1.z * w1.z + v1.w * w1.w;
  }
  float m = fmaxf(fmaxf(fmaxf(fabsf(v0.x), fabsf(v0.y)), fmaxf(fabsf(v0.z), fabsf(v0.w))),
                  fmaxf(fmaxf(fabsf(v1.x), fabsf(v1.y)), fmaxf(fabsf(v1.z), fabsf(v1.w))));
#pragma unroll
  for (int off = 1; off < 64; off <<= 1) {
    m = fmaxf(m, __shfl_xor(m, off));
#pragma unroll
    for (int s = 0; s < 4; ++s) a[s] += __shfl_xor(a[s], off);
  }
  __shared__ float redg[4][4];
  __shared__ float rmx[4];
  const int wv = tid >> 6;
  if ((tid & 63) == 0) {
    rmx[wv] = m;
#pragma unroll
    for (int s = 0; s < 4; ++s) redg[wv][s] = a[s];
  }
  __syncthreads();
  const float rm = fmaxf(fmaxf(rmx[0], rmx[1]), fmaxf(rmx[2], rmx[3]));
  const float inv = 127.0f / fmaxf(rm, 1e-30f);
  const int q0 = __float2int_rn(v0.x * inv), q1 = __float2int_rn(v0.y * inv);
  const int q2 = __float2int_rn(v0.z * inv), q3 = __float2int_rn(v0.w * inv);
  const int q4 = __float2int_rn(v1.x * inv), q5 = __float2int_rn(v1.y * inv);
  const int q6 = __float2int_rn(v1.z * inv), q7 = __float2int_rn(v1.w * inv);
  const int lo = (q0 & 255) | ((q1 & 255) << 8) | ((q2 & 255) << 16) | ((q3 & 255) << 24);
  const int hi = (q4 & 255) | ((q5 & 255) << 8) | ((q6 & 255) << 16) | ((q7 & 255) << 24);
  ((int2*)xq)[(size_t)b * 256 + tid] = make_int2(lo, hi);
  if (tid == 0) sx[b] = rm * (1.0f / 127.0f);
  if (tid < 4) {
    float v = redg[0][tid] + redg[1][tid] + redg[2][tid] + redg[3][tid] + bg[tid];
    gates[(size_t)b * 4 + tid] = 1.f / (1.f + __expf(-v));
  }
}

// ---- W row quantize: one block per (seg,d) row of 2048 ----
__global__ __launch_bounds__(256)
void wquant_kernel(const float* __restrict__ W, signed char* __restrict__ wq,
                   float* __restrict__ sw) {
  const int row = blockIdx.x;           // s*N_DIM + d
  const int tid = threadIdx.x;
  const size_t base = (size_t)row * K_DIM + tid * 8;
  const float4 v0 = *(const float4*)(W + base);
  const float4 v1 = *(const float4*)(W + base + 4);
  float m = fmaxf(fmaxf(fmaxf(fabsf(v0.x), fabsf(v0.y)), fmaxf(fabsf(v0.z), fabsf(v0.w))),
                  fmaxf(fmaxf(fabsf(v1.x), fabsf(v1.y)), fmaxf(fabsf(v1.z), fabsf(v1.w))));
#pragma unroll
  for (int off = 1; off < 64; off <<= 1) m = fmaxf(m, __shfl_xor(m, off));
  __shared__ float rmx[4];
  if ((tid & 63) == 0) rmx[tid >> 6] = m;
  __syncthreads();
  const float rm = fmaxf(fmaxf(rmx[0], rmx[1]), fmaxf(rmx[2], rmx[3]));
  const float inv = 127.0f / fmaxf(rm, 1e-30f);
  const int q0 = __float2int_rn(v0.x * inv), q1 = __float2int_rn(v0.y * inv);
  const int q2 = __float2int_rn(v0.z * inv), q3 = __float2int_rn(v0.w * inv);
  const int q4 = __float2int_rn(v1.x * inv), q5 = __float2int_rn(v1.y * inv);
  const int q6 = __float2int_rn(v1.z * inv), q7 = __float2int_rn(v1.w * inv);
  const int lo = (q0 & 255) | ((q1 & 255) << 8) | ((q2 & 255) << 16) | ((q3 & 255) << 24);
  const int hi = (q4 & 255) | ((q5 & 255) << 8) | ((q6 & 255) << 16) | ((q7 & 255) << 24);
  ((int2*)wq)[(size_t)row * 256 + tid] = make_int2(lo, hi);
  if (tid == 0) sw[row] = rm * (1.0f / 127.0f);
}

// ------- fused 4-segment GEMM, int8 16x16x64, 2 blocks/CU (4 waves/SIMD) ----
// NEW geometry: block 128 rows x 64 d x 4 segs; 8 waves 2Mx4N; per-wave
// 64 rows x 16 d x 4 segs -> acc v4i[4][4] = 64 VGPR. Lean live set
// (acc 64 + bfr 16 + a 16 + addr ~12) fits the 128-reg cap of
// __launch_bounds__(512,4) -> LDS 64 KiB -> TWO independent blocks per CU
// (4 waves/SIMD). Cross-block overlap hides LDS latency + barrier waits that
// intra-block scheduling could not (R5..R11 all ~flat at 2 waves/SIMD).
// LDS: A dbuf 2x8K (ONE gload_lds instr per tile) + B tri-buf 3x16K.
// Per wave per tile: 8 ds_read_b128 (4 B + 4 A), 16 MFMA, descending counted
// lgkm. Stages: A(t+1) at burst end, B(t+2) split mid-tile into dead 3rd
// buffer; tail vmcnt(2) (A(t+1)+B(t+1) landed, B(t+2)x2 flying); vmcnt(0)
// only at t==NT-2; 1 barrier/tile.
__global__ __launch_bounds__(512, 4)
void seg_gemm_kernel(const signed char* __restrict__ Xq,
                     const signed char* __restrict__ Wq,
                     const float* __restrict__ sx,
                     const float* __restrict__ sw,
                     const float* __restrict__ b_seg,
                     const float* __restrict__ thr,
                     const float* __restrict__ gates,
                     float* __restrict__ out) {
  __shared__ __align__(128) char smem[65536];   // A 16K | B 48K

  const int tid = threadIdx.x;
  const int lane = tid & 63;
  const int wid = tid >> 6;
  const int wm = wid >> 2;        // 0..1 (m half: 64 rows)
  const int wn = wid & 3;         // 0..3 (d quarter)

  // bijective XCD swizzle: 2048 blocks, 8 XCDs, 256 per XCD
  const int id = blockIdx.x;
  const int swz = (id & 7) * 256 + (id >> 3);
  const int m0 = (swz >> 5) * 128;      // 64 m-tiles
  const int n0 = (swz & 31) * 64;       // 32 n-tiles

  // ---- staging constants: A tile = 128 rows x 64B = 8KB = 1 instr ----
  const int row_st = tid >> 2;                       // 0..127
  const int kc    = (tid & 3) ^ ((tid >> 3) & 3);    // chunk swizzle (involution)
  const int keOff = kc * 16;
  const int ldsd  = tid * 16;                        // 0..8191

  // ---- read constants: row low4 = l15 on both A and B reads ----
  const int l15 = lane & 15;
  const int kg  = lane >> 4;       // 0..3
  const int aSw = l15 * 64 + ((kg ^ ((l15 >> 1) & 3)) << 4);

  v4i acc[NSEG][4];
#pragma unroll
  for (int s = 0; s < NSEG; ++s)
#pragma unroll
    for (int f = 0; f < 4; ++f) acc[s][f] = (v4i){0, 0, 0, 0};

#define STAGE_A(t_) do {                                                            \
    const signed char* s0_ = Xq + (size_t)(m0 + row_st) * K_DIM + (t_) * 64 + keOff; \
    __builtin_amdgcn_global_load_lds((gas_ptr)s0_, (lds_ptr)(smem + ((t_) & 1) * 8192 + ldsd), 16, 0, 0); \
  } while (0)

#define STAGE_B(t_, h_, bb_) do {                                                   \
    const signed char* s0_ = Wq + ((size_t)((h_) * 2 + (tid >> 8)) * N_DIM + (n0 + ((tid >> 2) & 63))) * K_DIM + (t_) * 64 + keOff; \
    __builtin_amdgcn_global_load_lds((gas_ptr)s0_, (lds_ptr)(smem + 16384 + (bb_) * 16384 + (h_) * 8192 + ldsd), 16, 0, 0); \
  } while (0)

#define MFMAI(a_, b_, c_) __builtin_amdgcn_mfma_i32_16x16x64_i8(a_, b_, c_, 0, 0, 0)
#define LD16(p_) (*(const v4i*)(p_))
#define WAITL(n_) asm volatile("s_waitcnt lgkmcnt(" #n_ ")" ::: "memory")

#define MM4(f_) do {                                                                \
    __builtin_amdgcn_s_setprio(1);                                                  \
    acc[0][(f_)] = MFMAI(a[(f_)], bfr[0], acc[0][(f_)]);                            \
    acc[1][(f_)] = MFMAI(a[(f_)], bfr[1], acc[1][(f_)]);                            \
    acc[2][(f_)] = MFMAI(a[(f_)], bfr[2], acc[2][(f_)]);                            \
    acc[3][(f_)] = MFMAI(a[(f_)], bfr[3], acc[3][(f_)]);                            \
    __builtin_amdgcn_s_setprio(0);                                                  \
  } while (0)

  // ---- prologue: A(0), B(0)->buf0, B(1)->buf1 (5 instr); keep B(1) flying --
  STAGE_A(0);
  STAGE_B(0, 0, 0); STAGE_B(0, 1, 0);
  STAGE_B(1, 0, 1); STAGE_B(1, 1, 1);
  asm volatile("s_waitcnt vmcnt(2)" ::: "memory");   // A(0),B(0) landed
  __builtin_amdgcn_s_barrier();

  int bc = 0, bs = 2;   // current / stage-target B buffer (mod 3)
  for (int t = 0; t < NT; ++t) {
    const char* Ab = smem + (t & 1) * 8192 + wm * 4096;
    const char* Bb = smem + 16384 + bc * 16384;
    v4i bfr[NSEG];
    v4i a[4];

    // ---- burst: 4 B + 4 A ds_reads, then A(t+1) stage (VMEM) ----
    bfr[0] = LD16(Bb + 0 * 4096 + wn * 1024 + aSw);
    bfr[1] = LD16(Bb + 1 * 4096 + wn * 1024 + aSw);
    bfr[2] = LD16(Bb + 2 * 4096 + wn * 1024 + aSw);
    bfr[3] = LD16(Bb + 3 * 4096 + wn * 1024 + aSw);
    a[0] = LD16(Ab + 0 * 1024 + aSw);
    a[1] = LD16(Ab + 1 * 1024 + aSw);
    a[2] = LD16(Ab + 2 * 1024 + aSw);
    a[3] = LD16(Ab + 3 * 1024 + aSw);
    if (t + 1 < NT) STAGE_A(t + 1);

    WAITL(3);  MM4(0);                               // b0-3 + a0 done
    WAITL(2);
    if (t + 2 < NT) STAGE_B(t + 2, 0, bs);
    MM4(1);
    WAITL(1);
    if (t + 2 < NT) STAGE_B(t + 2, 1, bs);
    MM4(2);
    WAITL(0);  MM4(3);

    if (t < NT - 2)      { asm volatile("s_waitcnt vmcnt(2)" ::: "memory"); }
    else if (t == NT - 2){ asm volatile("s_waitcnt vmcnt(0)" ::: "memory"); }
    __builtin_amdgcn_s_barrier();

    bc = (bc == 2) ? 0 : bc + 1;
    bs = (bs == 2) ? 0 : bs + 1;
  }
  asm volatile("s_waitcnt lgkmcnt(0) vmcnt(0)" ::: "memory");

  // ---------------- epilogue ----------------
  // C/D layout: col = lane&15 (d), row = (lane>>4)*4 + reg (dtype-independent)
  const int d = n0 + wn * 16 + l15;
  float bsv[NSEG], thv[NSEG], swv[NSEG];
#pragma unroll
  for (int s = 0; s < NSEG; ++s) {
    bsv[s] = b_seg[s * N_DIM + d];
    thv[s] = thr[s * N_DIM + d];
    swv[s] = sw[s * N_DIM + d];
  }
#pragma unroll
  for (int f = 0; f < 4; ++f) {
#pragma unroll
    for (int r = 0; r < 4; ++r) {
      const int brow = m0 + wm * 64 + f * 16 + kg * 4 + r;
      const float sxr = sx[brow];
      const float4 g = *(const float4*)(gates + (size_t)brow * 4);
      const float gv[NSEG] = {g.x, g.y, g.z, g.w};
      float sum = 0.f, prod = 1.f;
#pragma unroll
      for (int s = 0; s < NSEG; ++s) {
        const float seg = (float)acc[s][f][r] * (sxr * swv[s]) + bsv[s];
        const float pl = 1.f / (1.f + __expf(-5.f * (seg - thv[s])));
        const float st = seg * pl * gv[s];
        sum += st;
        prod *= st;
      }
      const float gm = sqrtf(sqrtf(fabsf(prod)));   // |prod|^(1/4)
      out[(size_t)brow * N_DIM + d] = sum + 0.1f * (prod < 0.f ? -gm : gm);
    }
  }
#undef STAGE_A
#undef STAGE_B
#undef MFMAI
#undef LD16
#undef WAITL
#undef MM4
}

extern "C" void kernel_launch(void* const* d_in, const int* in_sizes, int n_in,
                              void* d_out, int out_size, void* d_ws, size_t ws_size,
                              hipStream_t stream) {
  const float* x      = (const float*)d_in[0];
  const float* W_seg  = (const float*)d_in[1];
  const float* b_seg  = (const float*)d_in[2];
  const float* thr    = (const float*)d_in[3];
  const float* W_gate = (const float*)d_in[4];
  const float* b_gate = (const float*)d_in[5];
  float* out = (float*)d_out;

  // workspace: xq 16MB | wq 32MB | sx 32KB | sw 32KB | gates 128KB
  signed char* xq = (signed char*)d_ws;
  signed char* wq = xq + (size_t)B_DIM * K_DIM;
  float* sx = (float*)(wq + (size_t)NSEG * N_DIM * K_DIM);
  float* sw = sx + B_DIM;
  float* gates = sw + NSEG * N_DIM;

  xquant_gates_kernel<<<B_DIM, 256, 0, stream>>>(x, W_gate, b_gate, xq, sx, gates);
  wquant_kernel<<<NSEG * N_DIM, 256, 0, stream>>>(W_seg, wq, sw);

  seg_gemm_kernel<<<2048, 512, 0, stream>>>(xq, wq, sx, sw, b_seg, thr, gates, out);
}

// Round 14
// 219.164 us; speedup vs baseline: 1.0704x; 1.0704x over previous
//
#include <hip/hip_runtime.h>
#include <stdint.h>

#define B_DIM 8192
#define K_DIM 2048
#define N_DIM 2048
#define NSEG 4
#define NT (K_DIM / 64)   // 32 K-tiles of BK=64

typedef int v4i __attribute__((ext_vector_type(4)));

typedef const __attribute__((address_space(1))) void* gas_ptr;
typedef __attribute__((address_space(3))) void* lds_ptr;

// ---- fused: x row quantize (per-row int8) + gates = sigmoid(x@Wg^T+bg) ----
__global__ __launch_bounds__(256)
void xquant_gates_kernel(const float* __restrict__ x, const float* __restrict__ Wg,
                         const float* __restrict__ bg, signed char* __restrict__ xq,
                         float* __restrict__ sx, float* __restrict__ gates) {
  const int b = blockIdx.x;
  const int tid = threadIdx.x;
  const size_t base = (size_t)b * K_DIM + tid * 8;
  const float4 v0 = *(const float4*)(x + base);
  const float4 v1 = *(const float4*)(x + base + 4);

  float a[4];
#pragma unroll
  for (int s = 0; s < 4; ++s) {
    const float4 w0 = *(const float4*)(Wg + (size_t)s * K_DIM + tid * 8);
    const float4 w1 = *(const float4*)(Wg + (size_t)s * K_DIM + tid * 8 + 4);
    a[s] = v0.x * w0.x + v0.y * w0.y + v0.z * w0.z + v0.w * w0.w
         + v1.x * w1.x + v1.y * w1.y + v1.z * w1.z + v1.w * w1.w;
  }
  float m = fmaxf(fmaxf(fmaxf(fabsf(v0.x), fabsf(v0.y)), fmaxf(fabsf(v0.z), fabsf(v0.w))),
                  fmaxf(fmaxf(fabsf(v1.x), fabsf(v1.y)), fmaxf(fabsf(v1.z), fabsf(v1.w))));
#pragma unroll
  for (int off = 1; off < 64; off <<= 1) {
    m = fmaxf(m, __shfl_xor(m, off));
#pragma unroll
    for (int s = 0; s < 4; ++s) a[s] += __shfl_xor(a[s], off);
  }
  __shared__ float redg[4][4];
  __shared__ float rmx[4];
  const int wv = tid >> 6;
  if ((tid & 63) == 0) {
    rmx[wv] = m;
#pragma unroll
    for (int s = 0; s < 4; ++s) redg[wv][s] = a[s];
  }
  __syncthreads();
  const float rm = fmaxf(fmaxf(rmx[0], rmx[1]), fmaxf(rmx[2], rmx[3]));
  const float inv = 127.0f / fmaxf(rm, 1e-30f);
  const int q0 = __float2int_rn(v0.x * inv), q1 = __float2int_rn(v0.y * inv);
  const int q2 = __float2int_rn(v0.z * inv), q3 = __float2int_rn(v0.w * inv);
  const int q4 = __float2int_rn(v1.x * inv), q5 = __float2int_rn(v1.y * inv);
  const int q6 = __float2int_rn(v1.z * inv), q7 = __float2int_rn(v1.w * inv);
  const int lo = (q0 & 255) | ((q1 & 255) << 8) | ((q2 & 255) << 16) | ((q3 & 255) << 24);
  const int hi = (q4 & 255) | ((q5 & 255) << 8) | ((q6 & 255) << 16) | ((q7 & 255) << 24);
  ((int2*)xq)[(size_t)b * 256 + tid] = make_int2(lo, hi);
  if (tid == 0) sx[b] = rm * (1.0f / 127.0f);
  if (tid < 4) {
    float v = redg[0][tid] + redg[1][tid] + redg[2][tid] + redg[3][tid] + bg[tid];
    gates[(size_t)b * 4 + tid] = 1.f / (1.f + __expf(-v));
  }
}

// ---- W row quantize: one block per (seg,d) row of 2048 ----
__global__ __launch_bounds__(256)
void wquant_kernel(const float* __restrict__ W, signed char* __restrict__ wq,
                   float* __restrict__ sw) {
  const int row = blockIdx.x;           // s*N_DIM + d
  const int tid = threadIdx.x;
  const size_t base = (size_t)row * K_DIM + tid * 8;
  const float4 v0 = *(const float4*)(W + base);
  const float4 v1 = *(const float4*)(W + base + 4);
  float m = fmaxf(fmaxf(fmaxf(fabsf(v0.x), fabsf(v0.y)), fmaxf(fabsf(v0.z), fabsf(v0.w))),
                  fmaxf(fmaxf(fabsf(v1.x), fabsf(v1.y)), fmaxf(fabsf(v1.z), fabsf(v1.w))));
#pragma unroll
  for (int off = 1; off < 64; off <<= 1) m = fmaxf(m, __shfl_xor(m, off));
  __shared__ float rmx[4];
  if ((tid & 63) == 0) rmx[tid >> 6] = m;
  __syncthreads();
  const float rm = fmaxf(fmaxf(rmx[0], rmx[1]), fmaxf(rmx[2], rmx[3]));
  const float inv = 127.0f / fmaxf(rm, 1e-30f);
  const int q0 = __float2int_rn(v0.x * inv), q1 = __float2int_rn(v0.y * inv);
  const int q2 = __float2int_rn(v0.z * inv), q3 = __float2int_rn(v0.w * inv);
  const int q4 = __float2int_rn(v1.x * inv), q5 = __float2int_rn(v1.y * inv);
  const int q6 = __float2int_rn(v1.z * inv), q7 = __float2int_rn(v1.w * inv);
  const int lo = (q0 & 255) | ((q1 & 255) << 8) | ((q2 & 255) << 16) | ((q3 & 255) << 24);
  const int hi = (q4 & 255) | ((q5 & 255) << 8) | ((q6 & 255) << 16) | ((q7 & 255) << 24);
  ((int2*)wq)[(size_t)row * 256 + tid] = make_int2(lo, hi);
  if (tid == 0) sw[row] = rm * (1.0f / 127.0f);
}

// ------- fused 4-seg GEMM, i8 16x16x64: R12 schedule + L2-local mapping -----
// Geometry/schedule = R12 verbatim (passed, 196us): block 128 r x 64 d x
// 4 segs; 8 waves 2Mx4N; per-wave 64 r x 16 d x 4 segs; acc v4i[4][4];
// A dbuf 2x8K + B tri-ring 3x16K = 64 KB; 2 blocks/CU; reads AFTER the
// barrier (R13's pre-barrier prefetch raced on partner-wave staging).
// NEW: within-XCD 2D window mapping. Old mapping put all 32 n0 in each
// XCD's ~64-block concurrent window -> B working set 16.8 MB >> 4 MB L2 ->
// FETCH_SIZE 474 MB (14x inputs) at 2.4 TB/s of L3 traffic = the plateau.
// New: windows of 8 m0 x 8 n0 (A panel 2 MB stays L2-resident per XCD for
// the whole kernel; B window 4 MB with 8-way block reuse).
__global__ __launch_bounds__(512, 4)
void seg_gemm_kernel(const signed char* __restrict__ Xq,
                     const signed char* __restrict__ Wq,
                     const float* __restrict__ sx,
                     const float* __restrict__ sw,
                     const float* __restrict__ b_seg,
                     const float* __restrict__ thr,
                     const float* __restrict__ gates,
                     float* __restrict__ out) {
  __shared__ __align__(128) char smem[65536];   // A 16K | B 48K

  const int tid = threadIdx.x;
  const int lane = tid & 63;
  const int wid = tid >> 6;
  const int wm = wid >> 2;        // 0..1 (m half: 64 rows)
  const int wn = wid & 3;         // 0..3 (d quarter)

  // ---- XCD-local 2D window mapping (bijective) ----
  // XCD x gets c in [0,256): m_idx=(c>>3)&7 (8 m-panels resident in L2),
  // n_idx=(c&7)|((c>>6)<<3) -> concurrent ~64-block window = 8 m0 x 8 n0.
  const int id = blockIdx.x;
  const int x = id & 7;
  const int c = id >> 3;
  const int mIdx = (c >> 3) & 7;
  const int nIdx = (c & 7) | ((c >> 6) << 3);
  const int m0 = (x * 8 + mIdx) * 128;
  const int n0 = nIdx * 64;

  // ---- staging constants (verified zero-conflict, R10-R12) ----
  const int row_st = tid >> 2;                       // 0..127
  const int kc    = (tid & 3) ^ ((tid >> 3) & 3);    // chunk swizzle (involution)
  const int keOff = kc * 16;
  const int ldsd  = tid * 16;                        // 0..8191

  // ---- read constants (verified zero-conflict, R10-R12) ----
  const int l15 = lane & 15;
  const int kg  = lane >> 4;       // 0..3
  const int aSw = l15 * 64 + ((kg ^ ((l15 >> 1) & 3)) << 4);

  v4i acc[NSEG][4];
#pragma unroll
  for (int s = 0; s < NSEG; ++s)
#pragma unroll
    for (int f = 0; f < 4; ++f) acc[s][f] = (v4i){0, 0, 0, 0};

#define STAGE_A(t_) do {                                                            \
    const signed char* s0_ = Xq + (size_t)(m0 + row_st) * K_DIM + (t_) * 64 + keOff; \
    __builtin_amdgcn_global_load_lds((gas_ptr)s0_, (lds_ptr)(smem + ((t_) & 1) * 8192 + ldsd), 16, 0, 0); \
  } while (0)

#define STAGE_B(t_, h_, bb_) do {                                                   \
    const signed char* s0_ = Wq + ((size_t)((h_) * 2 + (tid >> 8)) * N_DIM + (n0 + ((tid >> 2) & 63))) * K_DIM + (t_) * 64 + keOff; \
    __builtin_amdgcn_global_load_lds((gas_ptr)s0_, (lds_ptr)(smem + 16384 + (bb_) * 16384 + (h_) * 8192 + ldsd), 16, 0, 0); \
  } while (0)

#define MFMAI(a_, b_, c_) __builtin_amdgcn_mfma_i32_16x16x64_i8(a_, b_, c_, 0, 0, 0)
#define LD16(p_) (*(const v4i*)(p_))
#define WAITL(n_) asm volatile("s_waitcnt lgkmcnt(" #n_ ")" ::: "memory")

#define MM4(f_) do {                                                                \
    __builtin_amdgcn_s_setprio(1);                                                  \
    acc[0][(f_)] = MFMAI(a[(f_)], bfr[0], acc[0][(f_)]);                            \
    acc[1][(f_)] = MFMAI(a[(f_)], bfr[1], acc[1][(f_)]);                            \
    acc[2][(f_)] = MFMAI(a[(f_)], bfr[2], acc[2][(f_)]);                            \
    acc[3][(f_)] = MFMAI(a[(f_)], bfr[3], acc[3][(f_)]);                            \
    __builtin_amdgcn_s_setprio(0);                                                  \
  } while (0)

  // ---- prologue: A(0), B(0)->buf0, B(1)->buf1 (5 instr); keep B(1) flying --
  STAGE_A(0);
  STAGE_B(0, 0, 0); STAGE_B(0, 1, 0);
  STAGE_B(1, 0, 1); STAGE_B(1, 1, 1);
  asm volatile("s_waitcnt vmcnt(2)" ::: "memory");   // A(0),B(0) landed
  __builtin_amdgcn_s_barrier();

  int bc = 0, bs = 2;   // current / stage-target B buffer (mod 3)
  for (int t = 0; t < NT; ++t) {
    const char* Ab = smem + (t & 1) * 8192 + wm * 4096;
    const char* Bb = smem + 16384 + bc * 16384;
    v4i bfr[NSEG];
    v4i a[4];

    // ---- burst: 4 B + 4 A ds_reads, then A(t+1) stage (VMEM) ----
    bfr[0] = LD16(Bb + 0 * 4096 + wn * 1024 + aSw);
    bfr[1] = LD16(Bb + 1 * 4096 + wn * 1024 + aSw);
    bfr[2] = LD16(Bb + 2 * 4096 + wn * 1024 + aSw);
    bfr[3] = LD16(Bb + 3 * 4096 + wn * 1024 + aSw);
    a[0] = LD16(Ab + 0 * 1024 + aSw);
    a[1] = LD16(Ab + 1 * 1024 + aSw);
    a[2] = LD16(Ab + 2 * 1024 + aSw);
    a[3] = LD16(Ab + 3 * 1024 + aSw);
    if (t + 1 < NT) STAGE_A(t + 1);

    WAITL(3);  MM4(0);                               // b0-3 + a0 done
    WAITL(2);
    if (t + 2 < NT) STAGE_B(t + 2, 0, bs);
    MM4(1);
    WAITL(1);
    if (t + 2 < NT) STAGE_B(t + 2, 1, bs);
    MM4(2);
    WAITL(0);  MM4(3);

    if (t < NT - 2)      { asm volatile("s_waitcnt vmcnt(2)" ::: "memory"); }
    else if (t == NT - 2){ asm volatile("s_waitcnt vmcnt(0)" ::: "memory"); }
    __builtin_amdgcn_s_barrier();

    bc = (bc == 2) ? 0 : bc + 1;
    bs = (bs == 2) ? 0 : bs + 1;
  }
  asm volatile("s_waitcnt lgkmcnt(0) vmcnt(0)" ::: "memory");

  // ---------------- epilogue ----------------
  // C/D layout: col = lane&15 (d), row = (lane>>4)*4 + reg (dtype-independent)
  const int d = n0 + wn * 16 + l15;
  float bsv[NSEG], thv[NSEG], swv[NSEG];
#pragma unroll
  for (int s = 0; s < NSEG; ++s) {
    bsv[s] = b_seg[s * N_DIM + d];
    thv[s] = thr[s * N_DIM + d];
    swv[s] = sw[s * N_DIM + d];
  }
#pragma unroll
  for (int f = 0; f < 4; ++f) {
#pragma unroll
    for (int r = 0; r < 4; ++r) {
      const int brow = m0 + wm * 64 + f * 16 + kg * 4 + r;
      const float sxr = sx[brow];
      const float4 g = *(const float4*)(gates + (size_t)brow * 4);
      const float gv[NSEG] = {g.x, g.y, g.z, g.w};
      float sum = 0.f, prod = 1.f;
#pragma unroll
      for (int s = 0; s < NSEG; ++s) {
        const float seg = (float)acc[s][f][r] * (sxr * swv[s]) + bsv[s];
        const float pl = 1.f / (1.f + __expf(-5.f * (seg - thv[s])));
        const float st = seg * pl * gv[s];
        sum += st;
        prod *= st;
      }
      const float gm = sqrtf(sqrtf(fabsf(prod)));   // |prod|^(1/4)
      out[(size_t)brow * N_DIM + d] = sum + 0.1f * (prod < 0.f ? -gm : gm);
    }
  }
#undef STAGE_A
#undef STAGE_B
#undef MFMAI
#undef LD16
#undef WAITL
#undef MM4
}

extern "C" void kernel_launch(void* const* d_in, const int* in_sizes, int n_in,
                              void* d_out, int out_size, void* d_ws, size_t ws_size,
                              hipStream_t stream) {
  const float* x      = (const float*)d_in[0];
  const float* W_seg  = (const float*)d_in[1];
  const float* b_seg  = (const float*)d_in[2];
  const float* thr    = (const float*)d_in[3];
  const float* W_gate = (const float*)d_in[4];
  const float* b_gate = (const float*)d_in[5];
  float* out = (float*)d_out;

  // workspace: xq 16MB | wq 32MB | sx 32KB | sw 32KB | gates 128KB
  signed char* xq = (signed char*)d_ws;
  signed char* wq = xq + (size_t)B_DIM * K_DIM;
  float* sx = (float*)(wq + (size_t)NSEG * N_DIM * K_DIM);
  float* sw = sx + B_DIM;
  float* gates = sw + NSEG * N_DIM;

  xquant_gates_kernel<<<B_DIM, 256, 0, stream>>>(x, W_gate, b_gate, xq, sx, gates);
  wquant_kernel<<<NSEG * N_DIM, 256, 0, stream>>>(W_seg, wq, sw);

  seg_gemm_kernel<<<2048, 512, 0, stream>>>(xq, wq, sx, sw, b_seg, thr, gates, out);
}